// Round 1
// baseline (621.249 us; speedup 1.0000x reference)
//
#include <hip/hip_runtime.h>
#include <hip/hip_bf16.h>

#define N_NODES 8192
#define F_INDIM 512
#define H1DIM   256
#define H2DIM   64

typedef __bf16 bf16x8 __attribute__((ext_vector_type(8)));
typedef float  floatx4 __attribute__((ext_vector_type(4)));

// ---------------- CSR build ----------------
__global__ void count_rows(const int* __restrict__ rows, int* __restrict__ cnt, int e) {
    int i = blockIdx.x * blockDim.x + threadIdx.x;
    if (i < e) atomicAdd(&cnt[rows[i]], 1);
}

// 8192 counts, one block of 1024 threads, 8 elems/thread
__global__ void scan_rows(const int* __restrict__ cnt, int* __restrict__ row_ptr,
                          int* __restrict__ cursor, int n) {
    __shared__ int sums[1024];
    int t = threadIdx.x;
    int base = t * 8;
    int loc[8];
    int s = 0;
#pragma unroll
    for (int i = 0; i < 8; ++i) { loc[i] = cnt[base + i]; s += loc[i]; }
    sums[t] = s;
    __syncthreads();
    for (int off = 1; off < 1024; off <<= 1) {
        int v = (t >= off) ? sums[t - off] : 0;
        __syncthreads();
        sums[t] += v;
        __syncthreads();
    }
    int run = sums[t] - s;  // exclusive prefix of this thread's chunk
#pragma unroll
    for (int i = 0; i < 8; ++i) {
        row_ptr[base + i] = run;
        cursor[base + i]  = run;
        run += loc[i];
    }
    if (t == 1023) row_ptr[n] = run;  // == E
}

__global__ void scatter_edges(const int* __restrict__ rows, const int* __restrict__ cols,
                              const float* __restrict__ vals, int* __restrict__ cursor,
                              int* __restrict__ csr_col, float* __restrict__ csr_val, int e) {
    int i = blockIdx.x * blockDim.x + threadIdx.x;
    if (i < e) {
        int r = rows[i];
        int slot = atomicAdd(&cursor[r], 1);
        csr_col[slot] = cols[i];
        csr_val[slot] = vals[i];
    }
}

// ---------------- f32 tiled GEMM (C = A[M,K] @ B[K,N]) ----------------
// BM=64 BN=64 BK=16 TM=TN=4, 256 threads
__global__ __launch_bounds__(256) void gemm_f32(const float* __restrict__ A,
                                                const float* __restrict__ B,
                                                float* __restrict__ C,
                                                int M, int N, int K) {
    constexpr int BM = 64, BN = 64, BK = 16, TM = 4, TN = 4;
    __shared__ float As[BK][BM];
    __shared__ float Bs[BK][BN];
    const int tid = threadIdx.x;
    const int tx = tid & 15;
    const int ty = tid >> 4;
    const int bm = blockIdx.y * BM;
    const int bn = blockIdx.x * BN;
    float acc[TM][TN] = {};
    for (int k0 = 0; k0 < K; k0 += BK) {
#pragma unroll
        for (int i = tid; i < BM * BK; i += 256) {
            int m = i >> 4, kk = i & 15;
            As[kk][m] = A[(size_t)(bm + m) * K + k0 + kk];
        }
#pragma unroll
        for (int i = tid; i < BK * BN; i += 256) {
            int kk = i >> 6, nn = i & 63;
            Bs[kk][nn] = B[(size_t)(k0 + kk) * N + bn + nn];
        }
        __syncthreads();
#pragma unroll
        for (int kk = 0; kk < BK; ++kk) {
            float a[TM], b[TN];
#pragma unroll
            for (int i = 0; i < TM; ++i) a[i] = As[kk][ty * TM + i];
#pragma unroll
            for (int j = 0; j < TN; ++j) b[j] = Bs[kk][tx * TN + j];
#pragma unroll
            for (int i = 0; i < TM; ++i)
#pragma unroll
                for (int j = 0; j < TN; ++j) acc[i][j] += a[i] * b[j];
        }
        __syncthreads();
    }
#pragma unroll
    for (int i = 0; i < TM; ++i)
#pragma unroll
        for (int j = 0; j < TN; ++j)
            C[(size_t)(bm + ty * TM + i) * N + bn + tx * TN + j] = acc[i][j];
}

// ---------------- CSR SpMM: out[r,:] = sum_e val_e * in[col_e,:] ----------------
template <int D, bool RELU>
__global__ __launch_bounds__(256) void spmm_csr(const int* __restrict__ row_ptr,
                                                const int* __restrict__ csr_col,
                                                const float* __restrict__ csr_val,
                                                const float* __restrict__ in,
                                                float* __restrict__ out,
                                                float* __restrict__ out2, int n) {
    constexpr int RPB = 256 / D;
    int r = blockIdx.x * RPB + threadIdx.x / D;
    int d = threadIdx.x % D;
    if (r >= n) return;
    int beg = row_ptr[r], end = row_ptr[r + 1];
    float acc = 0.f;
    for (int e = beg; e < end; ++e) {
        acc += csr_val[e] * in[csr_col[e] * D + d];
    }
    if (RELU) acc = fmaxf(acc, 0.f);
    out[r * D + d] = acc;
    if (out2) out2[r * D + d] = acc;
}

__global__ void f32_to_bf16(const float* __restrict__ in, __hip_bfloat16* __restrict__ out, int n) {
    int i = blockIdx.x * blockDim.x + threadIdx.x;
    if (i < n) out[i] = __float2bfloat16(in[i]);
}

// ---------------- adj_recon = z @ z^T via bf16 MFMA ----------------
// z_bf16: [8192, 64] bf16 (row = 128 B). Block = 4 waves, block tile 128x128,
// each wave computes a 64x64 tile = 4x4 grid of 16x16x32 MFMAs over K=64 (2 k-halves).
// A frag (lane L, khalf h): z[m0+mt*16+(L&15)][h*32 + (L>>4)*8 + j], j=0..7  (one 16B load)
// B frag symmetric from the n-rows (B[k][n] = z[n][k]).
// C/D layout: col = lane&15, row = (lane>>4)*4 + reg   [verified m89/m91]
__global__ __launch_bounds__(256) void zzt_mfma(const __hip_bfloat16* __restrict__ z,
                                                float* __restrict__ C) {
    const int tid = threadIdx.x;
    const int lane = tid & 63;
    const int wave = tid >> 6;
    const int wm = wave >> 1, wn = wave & 1;
    const int m0 = blockIdx.y * 128 + wm * 64;
    const int n0 = blockIdx.x * 128 + wn * 64;
    const int r16 = lane & 15;
    const int quad = lane >> 4;

    floatx4 acc[4][4] = {};
    const char* zb = (const char*)z;

#pragma unroll
    for (int h = 0; h < 2; ++h) {
        bf16x8 a[4], b[4];
#pragma unroll
        for (int mt = 0; mt < 4; ++mt) {
            int row = m0 + mt * 16 + r16;
            a[mt] = *(const bf16x8*)(zb + row * 128 + h * 64 + quad * 16);
        }
#pragma unroll
        for (int nt = 0; nt < 4; ++nt) {
            int row = n0 + nt * 16 + r16;
            b[nt] = *(const bf16x8*)(zb + row * 128 + h * 64 + quad * 16);
        }
#pragma unroll
        for (int mt = 0; mt < 4; ++mt)
#pragma unroll
            for (int nt = 0; nt < 4; ++nt)
                acc[mt][nt] = __builtin_amdgcn_mfma_f32_16x16x32_bf16(a[mt], b[nt], acc[mt][nt], 0, 0, 0);
    }

#pragma unroll
    for (int mt = 0; mt < 4; ++mt)
#pragma unroll
        for (int nt = 0; nt < 4; ++nt)
#pragma unroll
            for (int r = 0; r < 4; ++r) {
                int row = m0 + mt * 16 + quad * 4 + r;
                int col = n0 + nt * 16 + r16;
                C[(size_t)row * N_NODES + col] = acc[mt][nt][r];
            }
}

// ---------------- launch ----------------
extern "C" void kernel_launch(void* const* d_in, const int* in_sizes, int n_in,
                              void* d_out, int out_size, void* d_ws, size_t ws_size,
                              hipStream_t stream) {
    const float* x        = (const float*)d_in[0];
    const int*   adj_rows = (const int*)d_in[1];
    const int*   adj_cols = (const int*)d_in[2];
    const float* adj_vals = (const float*)d_in[3];
    const float* W1       = (const float*)d_in[4];
    const float* W2       = (const float*)d_in[5];
    const float* W3       = (const float*)d_in[6];
    const int E = in_sizes[1];
    const int n = N_NODES;

    char* ws = (char*)d_ws;
    size_t off = 0;
    auto alloc = [&](size_t bytes) {
        void* p = ws + off;
        off = (off + bytes + 255) & ~(size_t)255;
        return p;
    };
    int*   cnt     = (int*)alloc((size_t)n * 4);
    int*   row_ptr = (int*)alloc((size_t)(n + 1) * 4);
    int*   cursor  = (int*)alloc((size_t)n * 4);
    int*   csr_col = (int*)alloc((size_t)E * 4);
    float* csr_val = (float*)alloc((size_t)E * 4);
    float* support = (float*)alloc((size_t)n * H1DIM * 4);
    float* h1      = (float*)alloc((size_t)n * H1DIM * 4);
    float* t2      = (float*)alloc((size_t)n * H2DIM * 4);
    float* t3      = (float*)alloc((size_t)n * H2DIM * 4);
    __hip_bfloat16* zb = (__hip_bfloat16*)alloc((size_t)n * H2DIM * 2);

    float* out        = (float*)d_out;
    float* adj_recon  = out;                          // [8192,8192]
    float* z_out      = out + (size_t)n * n;          // [8192,64]
    float* mu_out     = z_out + (size_t)n * H2DIM;
    float* logvar_out = mu_out + (size_t)n * H2DIM;

    // CSR build
    hipMemsetAsync(cnt, 0, (size_t)n * 4, stream);
    count_rows<<<(E + 255) / 256, 256, 0, stream>>>(adj_rows, cnt, E);
    scan_rows<<<1, 1024, 0, stream>>>(cnt, row_ptr, cursor, n);
    scatter_edges<<<(E + 255) / 256, 256, 0, stream>>>(adj_rows, adj_cols, adj_vals,
                                                       cursor, csr_col, csr_val, E);

    // gc1: support = x @ W1 ; h1 = relu(spmm(support))
    gemm_f32<<<dim3(H1DIM / 64, n / 64), 256, 0, stream>>>(x, W1, support, n, H1DIM, F_INDIM);
    spmm_csr<256, true><<<n, 256, 0, stream>>>(row_ptr, csr_col, csr_val, support, h1, nullptr, n);

    // gc2/gc3: mu = spmm(h1@W2), logvar = spmm(h1@W3); z = mu
    gemm_f32<<<dim3(H2DIM / 64, n / 64), 256, 0, stream>>>(h1, W2, t2, n, H2DIM, H1DIM);
    gemm_f32<<<dim3(H2DIM / 64, n / 64), 256, 0, stream>>>(h1, W3, t3, n, H2DIM, H1DIM);
    spmm_csr<64, false><<<n / 4, 256, 0, stream>>>(row_ptr, csr_col, csr_val, t2, mu_out, z_out, n);
    spmm_csr<64, false><<<n / 4, 256, 0, stream>>>(row_ptr, csr_col, csr_val, t3, logvar_out, nullptr, n);

    // decoder: adj_recon = z @ z^T (bf16 MFMA)
    f32_to_bf16<<<(n * H2DIM + 255) / 256, 256, 0, stream>>>(mu_out, zb, n * H2DIM);
    zzt_mfma<<<dim3(n / 128, n / 128), 256, 0, stream>>>(zb, adj_recon);
}

// Round 2
// 445.443 us; speedup vs baseline: 1.3947x; 1.3947x over previous
//
#include <hip/hip_runtime.h>
#include <hip/hip_bf16.h>

#define N_NODES 8192
#define F_INDIM 512
#define H1DIM   256
#define H2DIM   64

typedef __bf16 bf16x8 __attribute__((ext_vector_type(8)));
typedef float  floatx4 __attribute__((ext_vector_type(4)));

// ---------------- CSR build ----------------
__global__ void count_rows(const int* __restrict__ rows, int* __restrict__ cnt, int e) {
    int i = blockIdx.x * blockDim.x + threadIdx.x;
    if (i < e) atomicAdd(&cnt[rows[i]], 1);
}

__global__ void scan_rows(const int* __restrict__ cnt, int* __restrict__ row_ptr,
                          int* __restrict__ cursor, int n) {
    __shared__ int sums[1024];
    int t = threadIdx.x;
    int base = t * 8;
    int loc[8];
    int s = 0;
#pragma unroll
    for (int i = 0; i < 8; ++i) { loc[i] = cnt[base + i]; s += loc[i]; }
    sums[t] = s;
    __syncthreads();
    for (int off = 1; off < 1024; off <<= 1) {
        int v = (t >= off) ? sums[t - off] : 0;
        __syncthreads();
        sums[t] += v;
        __syncthreads();
    }
    int run = sums[t] - s;
#pragma unroll
    for (int i = 0; i < 8; ++i) {
        row_ptr[base + i] = run;
        cursor[base + i]  = run;
        run += loc[i];
    }
    if (t == 1023) row_ptr[n] = run;
}

__global__ void scatter_edges(const int* __restrict__ rows, const int* __restrict__ cols,
                              const float* __restrict__ vals, int* __restrict__ cursor,
                              int* __restrict__ csr_col, float* __restrict__ csr_val, int e) {
    int i = blockIdx.x * blockDim.x + threadIdx.x;
    if (i < e) {
        int r = rows[i];
        int slot = atomicAdd(&cursor[r], 1);
        csr_col[slot] = cols[i];
        csr_val[slot] = vals[i];
    }
}

// ---------------- gemm1: support = x[8192,512] @ W1[512,256] ----------------
// BM=64 BN=64 BK=16, 256 thr, TM=TN=4, float4 LDS reads, padded stride 68
__global__ __launch_bounds__(256) void gemm1_f32(const float* __restrict__ A,
                                                 const float* __restrict__ B,
                                                 float* __restrict__ C) {
    constexpr int K = F_INDIM, NN = H1DIM;
    constexpr int BK = 16, LD = 68;  // 64+4 pad: 16B-aligned rows, <=2-way banks
    __shared__ float As[BK][LD];
    __shared__ float Bs[BK][LD];
    const int tid = threadIdx.x;
    const int tx = tid & 15;
    const int ty = tid >> 4;
    const int bm = blockIdx.y * 64;
    const int bn = blockIdx.x * 64;
    float acc[4][4] = {};

    const int arow = tid >> 2, akc = (tid & 3) * 4;   // A stage: 64 rows x 16 k
    const int bkk = tid >> 4, bnc = (tid & 15) * 4;   // B stage: 16 k x 64 n

    for (int k0 = 0; k0 < K; k0 += BK) {
        floatx4 av = *(const floatx4*)&A[(size_t)(bm + arow) * K + k0 + akc];
#pragma unroll
        for (int j = 0; j < 4; ++j) As[akc + j][arow] = av[j];  // transpose scatter
        *(floatx4*)&Bs[bkk][bnc] = *(const floatx4*)&B[(size_t)(k0 + bkk) * NN + bn + bnc];
        __syncthreads();
#pragma unroll
        for (int kk = 0; kk < BK; ++kk) {
            floatx4 a = *(const floatx4*)&As[kk][ty * 4];
            floatx4 b = *(const floatx4*)&Bs[kk][tx * 4];
#pragma unroll
            for (int i = 0; i < 4; ++i)
#pragma unroll
                for (int j = 0; j < 4; ++j) acc[i][j] += a[i] * b[j];
        }
        __syncthreads();
    }
#pragma unroll
    for (int i = 0; i < 4; ++i) {
        floatx4 o = {acc[i][0], acc[i][1], acc[i][2], acc[i][3]};
        *(floatx4*)&C[(size_t)(bm + ty * 4 + i) * NN + bn + tx * 4] = o;
    }
}

// ---------------- gemm23: t2 = h1 @ W2, t3 = h1 @ W3 (fused, read h1 once) ----
// BM=64 BN=128(64+64) BK=16, 256 thr, TM=4 TN=8
__global__ __launch_bounds__(256) void gemm23_f32(const float* __restrict__ A,
                                                  const float* __restrict__ W2,
                                                  const float* __restrict__ W3,
                                                  float* __restrict__ C2,
                                                  float* __restrict__ C3) {
    constexpr int K = H1DIM, NO = H2DIM;
    constexpr int BK = 16, LDA = 68, LDB = 136;  // both 16B-aligned strides
    __shared__ float As[BK][LDA];
    __shared__ float Bs[BK][LDB];
    const int tid = threadIdx.x;
    const int tx = tid & 15;   // 16 x 8 cols = 128
    const int ty = tid >> 4;   // 16 x 4 rows = 64
    const int bm = blockIdx.x * 64;
    float acc[4][8] = {};

    const int arow = tid >> 2, akc = (tid & 3) * 4;

    for (int k0 = 0; k0 < K; k0 += BK) {
        floatx4 av = *(const floatx4*)&A[(size_t)(bm + arow) * K + k0 + akc];
#pragma unroll
        for (int j = 0; j < 4; ++j) As[akc + j][arow] = av[j];
#pragma unroll
        for (int v = 0; v < 2; ++v) {
            int idx = tid + v * 256;          // 512 float4s = 16k x 32
            int kk = idx >> 5, nc = (idx & 31) * 4;
            const float* src = (nc < 64) ? &W2[(size_t)(k0 + kk) * NO + nc]
                                         : &W3[(size_t)(k0 + kk) * NO + nc - 64];
            *(floatx4*)&Bs[kk][nc] = *(const floatx4*)src;
        }
        __syncthreads();
#pragma unroll
        for (int kk = 0; kk < BK; ++kk) {
            floatx4 a = *(const floatx4*)&As[kk][ty * 4];
            floatx4 b0 = *(const floatx4*)&Bs[kk][tx * 8];
            floatx4 b1 = *(const floatx4*)&Bs[kk][tx * 8 + 4];
#pragma unroll
            for (int i = 0; i < 4; ++i) {
#pragma unroll
                for (int j = 0; j < 4; ++j) acc[i][j] += a[i] * b0[j];
#pragma unroll
                for (int j = 0; j < 4; ++j) acc[i][j + 4] += a[i] * b1[j];
            }
        }
        __syncthreads();
    }
    const int c0 = tx * 8;  // stays within one half (tx<8 -> W2, tx>=8 -> W3)
#pragma unroll
    for (int i = 0; i < 4; ++i) {
        floatx4 o0 = {acc[i][0], acc[i][1], acc[i][2], acc[i][3]};
        floatx4 o1 = {acc[i][4], acc[i][5], acc[i][6], acc[i][7]};
        size_t row = bm + ty * 4 + i;
        if (c0 < 64) {
            *(floatx4*)&C2[row * NO + c0] = o0;
            *(floatx4*)&C2[row * NO + c0 + 4] = o1;
        } else {
            *(floatx4*)&C3[row * NO + c0 - 64] = o0;
            *(floatx4*)&C3[row * NO + c0 - 60] = o1;
        }
    }
}

// ---------------- spmm1: h1 = relu(A_sp @ support), D=256, LDS-staged edges --
__global__ __launch_bounds__(256) void spmm_h1(const int* __restrict__ row_ptr,
                                               const int* __restrict__ csr_col,
                                               const float* __restrict__ csr_val,
                                               const float* __restrict__ in,
                                               float* __restrict__ out) {
    __shared__ int   s_col[256];
    __shared__ float s_val[256];
    const int r = blockIdx.x;
    const int d = threadIdx.x;
    const int beg = row_ptr[r];
    const int deg = row_ptr[r + 1] - beg;
    float acc = 0.f;
    for (int base = 0; base < deg; base += 256) {
        __syncthreads();
        if (base + d < deg) {
            s_col[d] = csr_col[beg + base + d];
            s_val[d] = csr_val[beg + base + d];
        }
        __syncthreads();
        int m = deg - base; if (m > 256) m = 256;
        int e = 0;
        for (; e + 4 <= m; e += 4) {
            float x0 = in[(size_t)s_col[e]     * H1DIM + d];
            float x1 = in[(size_t)s_col[e + 1] * H1DIM + d];
            float x2 = in[(size_t)s_col[e + 2] * H1DIM + d];
            float x3 = in[(size_t)s_col[e + 3] * H1DIM + d];
            acc += s_val[e] * x0 + s_val[e + 1] * x1 + s_val[e + 2] * x2 + s_val[e + 3] * x3;
        }
        for (; e < m; ++e) acc += s_val[e] * in[(size_t)s_col[e] * H1DIM + d];
    }
    out[(size_t)r * H1DIM + d] = fmaxf(acc, 0.f);
}

// ---------------- spmm23: mu/z/logvar/zb from t2,t3; 2 rows per block -------
__global__ __launch_bounds__(256) void spmm_mu_logvar(const int* __restrict__ row_ptr,
                                                      const int* __restrict__ csr_col,
                                                      const float* __restrict__ csr_val,
                                                      const float* __restrict__ t2,
                                                      const float* __restrict__ t3,
                                                      float* __restrict__ mu,
                                                      float* __restrict__ z,
                                                      float* __restrict__ logvar,
                                                      __hip_bfloat16* __restrict__ zb) {
    __shared__ int   s_col[2][128];
    __shared__ float s_val[2][128];
    __shared__ int   s_deg[2];
    const int tid = threadIdx.x;
    const int half = tid >> 7;
    const int d = tid & 127;
    const int r = blockIdx.x * 2 + half;
    const int beg = row_ptr[r];
    const int deg = row_ptr[r + 1] - beg;
    if (d == 0) s_deg[half] = deg;
    __syncthreads();
    const int trips = (max(s_deg[0], s_deg[1]) + 127) >> 7;
    const float* src = (d < 64) ? t2 : t3;
    const int dd = d & 63;
    float acc = 0.f;
    for (int t = 0; t < trips; ++t) {
        int base = t * 128;
        __syncthreads();
        if (base + d < deg) {
            s_col[half][d] = csr_col[beg + base + d];
            s_val[half][d] = csr_val[beg + base + d];
        }
        __syncthreads();
        int m = deg - base; if (m > 128) m = 128; if (m < 0) m = 0;
        int e = 0;
        for (; e + 4 <= m; e += 4) {
            float x0 = src[(size_t)s_col[half][e]     * H2DIM + dd];
            float x1 = src[(size_t)s_col[half][e + 1] * H2DIM + dd];
            float x2 = src[(size_t)s_col[half][e + 2] * H2DIM + dd];
            float x3 = src[(size_t)s_col[half][e + 3] * H2DIM + dd];
            acc += s_val[half][e] * x0 + s_val[half][e + 1] * x1
                 + s_val[half][e + 2] * x2 + s_val[half][e + 3] * x3;
        }
        for (; e < m; ++e) acc += s_val[half][e] * src[(size_t)s_col[half][e] * H2DIM + dd];
    }
    size_t o = (size_t)r * H2DIM + dd;
    if (d < 64) {
        mu[o] = acc;
        z[o] = acc;
        zb[o] = __float2bfloat16(acc);
    } else {
        logvar[o] = acc;
    }
}

// ---------------- adj_recon = z @ z^T via bf16 MFMA ----------------
__global__ __launch_bounds__(256) void zzt_mfma(const __hip_bfloat16* __restrict__ z,
                                                float* __restrict__ C) {
    const int tid = threadIdx.x;
    const int lane = tid & 63;
    const int wave = tid >> 6;
    const int wm = wave >> 1, wn = wave & 1;
    const int m0 = blockIdx.y * 128 + wm * 64;
    const int n0 = blockIdx.x * 128 + wn * 64;
    const int r16 = lane & 15;
    const int quad = lane >> 4;

    floatx4 acc[4][4] = {};
    const char* zb = (const char*)z;

#pragma unroll
    for (int h = 0; h < 2; ++h) {
        bf16x8 a[4], b[4];
#pragma unroll
        for (int mt = 0; mt < 4; ++mt)
            a[mt] = *(const bf16x8*)(zb + (m0 + mt * 16 + r16) * 128 + h * 64 + quad * 16);
#pragma unroll
        for (int nt = 0; nt < 4; ++nt)
            b[nt] = *(const bf16x8*)(zb + (n0 + nt * 16 + r16) * 128 + h * 64 + quad * 16);
#pragma unroll
        for (int mt = 0; mt < 4; ++mt)
#pragma unroll
            for (int nt = 0; nt < 4; ++nt)
                acc[mt][nt] = __builtin_amdgcn_mfma_f32_16x16x32_bf16(a[mt], b[nt], acc[mt][nt], 0, 0, 0);
    }

#pragma unroll
    for (int mt = 0; mt < 4; ++mt)
#pragma unroll
        for (int nt = 0; nt < 4; ++nt)
#pragma unroll
            for (int r = 0; r < 4; ++r) {
                int row = m0 + mt * 16 + quad * 4 + r;
                int col = n0 + nt * 16 + r16;
                C[(size_t)row * N_NODES + col] = acc[mt][nt][r];
            }
}

// ---------------- launch ----------------
extern "C" void kernel_launch(void* const* d_in, const int* in_sizes, int n_in,
                              void* d_out, int out_size, void* d_ws, size_t ws_size,
                              hipStream_t stream) {
    const float* x        = (const float*)d_in[0];
    const int*   adj_rows = (const int*)d_in[1];
    const int*   adj_cols = (const int*)d_in[2];
    const float* adj_vals = (const float*)d_in[3];
    const float* W1       = (const float*)d_in[4];
    const float* W2       = (const float*)d_in[5];
    const float* W3       = (const float*)d_in[6];
    const int E = in_sizes[1];
    const int n = N_NODES;

    char* ws = (char*)d_ws;
    size_t off = 0;
    auto alloc = [&](size_t bytes) {
        void* p = ws + off;
        off = (off + bytes + 255) & ~(size_t)255;
        return p;
    };
    int*   cnt     = (int*)alloc((size_t)n * 4);
    int*   row_ptr = (int*)alloc((size_t)(n + 1) * 4);
    int*   cursor  = (int*)alloc((size_t)n * 4);
    int*   csr_col = (int*)alloc((size_t)E * 4);
    float* csr_val = (float*)alloc((size_t)E * 4);
    float* support = (float*)alloc((size_t)n * H1DIM * 4);
    float* h1      = (float*)alloc((size_t)n * H1DIM * 4);
    float* t2      = (float*)alloc((size_t)n * H2DIM * 4);
    float* t3      = (float*)alloc((size_t)n * H2DIM * 4);
    __hip_bfloat16* zb = (__hip_bfloat16*)alloc((size_t)n * H2DIM * 2);

    float* out        = (float*)d_out;
    float* adj_recon  = out;
    float* z_out      = out + (size_t)n * n;
    float* mu_out     = z_out + (size_t)n * H2DIM;
    float* logvar_out = mu_out + (size_t)n * H2DIM;

    // CSR build
    hipMemsetAsync(cnt, 0, (size_t)n * 4, stream);
    count_rows<<<(E + 255) / 256, 256, 0, stream>>>(adj_rows, cnt, E);
    scan_rows<<<1, 1024, 0, stream>>>(cnt, row_ptr, cursor, n);
    scatter_edges<<<(E + 255) / 256, 256, 0, stream>>>(adj_rows, adj_cols, adj_vals,
                                                       cursor, csr_col, csr_val, E);

    // gc1
    gemm1_f32<<<dim3(H1DIM / 64, n / 64), 256, 0, stream>>>(x, W1, support);
    spmm_h1<<<n, 256, 0, stream>>>(row_ptr, csr_col, csr_val, support, h1);

    // gc2 / gc3 fused
    gemm23_f32<<<n / 64, 256, 0, stream>>>(h1, W2, W3, t2, t3);
    spmm_mu_logvar<<<n / 2, 256, 0, stream>>>(row_ptr, csr_col, csr_val, t2, t3,
                                              mu_out, z_out, logvar_out, zb);

    // decoder
    zzt_mfma<<<dim3(n / 128, n / 128), 256, 0, stream>>>(zb, adj_recon);
}